// Round 17
// baseline (148.988 us; speedup 1.0000x reference)
//
#include <hip/hip_runtime.h>
#include <hip/hip_bf16.h>
#include <math.h>

// Dims (fixed by the problem)
#define B_  4
#define CIN 256
#define L_  4096      // H*W = 64*64
#define D_  256
#define N_  512
#define K_  4
#define DH  128       // D/2
#define BL  (B_ * L_) // 16384 tokens

#define NCHUNK 256
#define CLEN   (L_ / NCHUNK) // 16

typedef __attribute__((ext_vector_type(8))) short bfrag;
typedef __attribute__((ext_vector_type(4))) float f4;

__device__ __forceinline__ float bf2f(unsigned short u) {
  return __uint_as_float(((unsigned int)u) << 16);
}
__device__ __forceinline__ unsigned short f2bf(float f) {
  unsigned int u = __float_as_uint(f);
  return (unsigned short)((u + 0x7FFFu + ((u >> 16) & 1u)) >> 16);
}

// ---------------------------------------------------------------- prep (all weight converts, 1 launch)
// Bb16 row (n*4+k) = B_base[k,n,:]   (K-contig over d)
// Cb16 row (d*4+k) = C_base[k,d,:]   (K-contig over n)
__global__ void k_prep(const float* __restrict__ Wf, const float* __restrict__ Whf,
                       const float* __restrict__ Wa1, const float* __restrict__ Wout,
                       const float* __restrict__ Bb, const float* __restrict__ Cb,
                       const float* __restrict__ bfv, const float* __restrict__ bhfv,
                       unsigned short* __restrict__ Wfb /*Wfb+Whfb adjacent*/,
                       unsigned short* __restrict__ Wa1b,
                       unsigned short* __restrict__ Woutb,
                       unsigned short* __restrict__ Bb16,
                       unsigned short* __restrict__ Cb16,
                       float* __restrict__ biascat) {
  int i = blockIdx.x * 256 + threadIdx.x;
  if (i < 65536) { Wfb[i] = f2bf(Wf[i]); return; } i -= 65536;
  if (i < 65536) { Wfb[65536 + i] = f2bf(Whf[i]); return; } i -= 65536;
  if (i < 32768) { Wa1b[i] = f2bf(Wa1[i]); return; } i -= 32768;
  if (i < 65536) { Woutb[i] = f2bf(Wout[i]); return; } i -= 65536;
  if (i < 524288) {  // B_base (K,N,D): i = (k<<17)|(n<<8)|d
    int d = i & 255, n = (i >> 8) & 511, k = i >> 17;
    Bb16[(((size_t)n << 2) | k) << 8 | d] = f2bf(Bb[i]);
    return;
  } i -= 524288;
  if (i < 524288) {  // C_base (K,D,N): i = (k<<17)|(d<<9)|nn
    int nn = i & 511, d = (i >> 9) & 255, k = i >> 17;
    Cb16[(((size_t)d << 2) | k) << 9 | nn] = f2bf(Cb[i]);
    return;
  } i -= 524288;
  if (i < 256) { biascat[i] = bfv[i]; return; } i -= 256;
  if (i < 256) { biascat[256 + i] = bhfv[i]; }
}

// feat/hf (B,C,L) f32 -> (B*L, C) bf16 ; z = which*4 + b
__global__ void k_transpose2(const float* __restrict__ feat, const float* __restrict__ hf,
                             unsigned short* __restrict__ featT /* hfT adjacent */) {
  __shared__ float tile[32][33];
  const int z = blockIdx.z;
  const int b = z & 3, which = z >> 2;
  const float* in = which ? hf : feat;
  unsigned short* outT = featT + (size_t)which * BL * CIN;
  const int l0 = blockIdx.x * 32, c0 = blockIdx.y * 32;
  const int tx = threadIdx.x, ty = threadIdx.y;
  const float* p = in + ((size_t)b * CIN + c0 + ty) * L_ + l0 + tx;
#pragma unroll
  for (int i = 0; i < 32; i += 8) tile[ty + i][tx] = p[(size_t)i * L_];
  __syncthreads();
  unsigned short* q = outT + ((size_t)b * L_ + l0 + ty) * CIN + c0 + tx;
#pragma unroll
  for (int i = 0; i < 32; i += 8) q[(size_t)i * CIN] = f2bf(tile[tx][ty + i]);
}

// ---------------------------------------------------------------- scan (3-pass)
// a recomputed from alpha & A_base in-register; u read as bf16.

__global__ void k_scanA(const unsigned short* __restrict__ u, const float* __restrict__ alpha,
                        const float* __restrict__ Abase,
                        float* __restrict__ P, float* __restrict__ Hend) {
  const int n = threadIdx.x;           // 512
  const int bc = blockIdx.x;           // B*NCHUNK = 1024
  const int b = bc / NCHUNK, c = bc % NCHUNK;
  const float A0 = Abase[n], A1 = Abase[N_ + n], A2 = Abase[2 * N_ + n], A3 = Abase[3 * N_ + n];
  const size_t tok0 = (size_t)b * L_ + (size_t)c * CLEN;
  float p = 1.f, h = 0.f;
  for (int l = 0; l < CLEN; ++l) {
    const size_t t = tok0 + l;
    float4 al = *(const float4*)(alpha + t * 4);
    float s = al.x * A0 + al.y * A1 + al.z * A2 + al.w * A3;
    float av = 1.f / (1.f + expf(-s));
    float uv = bf2f(u[t * N_ + n]);
    h = av * h + uv;
    p *= av;
  }
  P[(size_t)bc * N_ + n] = p;
  Hend[(size_t)bc * N_ + n] = h;
}

__global__ void k_scanB(const float* __restrict__ P, const float* __restrict__ Hend,
                        float* __restrict__ Hstart) {
  const int n = threadIdx.x;
  const int b = blockIdx.x;
  float h = 0.f;
  for (int c = 0; c < NCHUNK; ++c) {
    size_t idx = ((size_t)b * NCHUNK + c) * N_ + n;
    Hstart[idx] = h;
    h = P[idx] * h + Hend[idx];
  }
}

__global__ void k_scanC(const unsigned short* __restrict__ u, const float* __restrict__ alpha,
                        const float* __restrict__ Abase, const float* __restrict__ Hstart,
                        unsigned short* __restrict__ hbf) {
  const int n = threadIdx.x;
  const int bc = blockIdx.x;
  const int b = bc / NCHUNK, c = bc % NCHUNK;
  const float A0 = Abase[n], A1 = Abase[N_ + n], A2 = Abase[2 * N_ + n], A3 = Abase[3 * N_ + n];
  const size_t tok0 = (size_t)b * L_ + (size_t)c * CLEN;
  float h = Hstart[(size_t)bc * N_ + n];
  for (int l = 0; l < CLEN; ++l) {
    const size_t t = tok0 + l;
    float4 al = *(const float4*)(alpha + t * 4);
    float s = al.x * A0 + al.y * A1 + al.z * A2 + al.w * A3;
    float av = 1.f / (1.f + expf(-s));
    float uv = bf2f(u[t * N_ + n]);
    h = av * h + uv;
    hbf[t * N_ + n] = f2bf(h);
  }
}

// ---------------------------------------------------------------- GEMM common
// LDS XOR swizzle (T2, rule #21 both-sides): 64-B rows, slot(16B) ^= (row>>1)&3.
#define BM 128
#define BN 128
#define BK 32

#define GLL(src, dst)                                                                      \
  __builtin_amdgcn_global_load_lds((const __attribute__((address_space(1))) void*)(src),   \
                                   (__attribute__((address_space(3))) void*)(dst), 16, 0, 0)

// ---- engine 2: 512-thread 128x256, 2-SLOT LDS (48 KB -> 3 blocks/CU), counted
// vmcnt + raw barrier. EPI: 3 = alpha-mix -> bf16 (ld=N/4).
#define BM2 128
#define BN2 256

template <int BIAS, int EPI>
__global__ __launch_bounds__(512, 2) void gemm_bt2(
    const unsigned short* __restrict__ A, long sA,
    const unsigned short* __restrict__ Bm, long sB,
    const float* __restrict__ bias, long bS,
    const float* __restrict__ alphaP,
    void* __restrict__ Cv, long sC,
    int M, int N, int Kd, int lda, int ldb) {
  const int zb = blockIdx.z;
  A += (size_t)zb * sA;
  Bm += (size_t)zb * sB;
  if (BIAS) bias += (size_t)zb * bS;
  const int m0 = blockIdx.x * BM2;
  const int n0 = blockIdx.y * BN2;
  __shared__ __attribute__((aligned(16))) unsigned short As[2 * BM2 * BK]; // 16 KB
  __shared__ __attribute__((aligned(16))) unsigned short Bs[2 * BN2 * BK]; // 32 KB
  const int t = threadIdx.x;
  const int lane = t & 63;
  const int w = t >> 6;
  const int wm = (w >> 2) * 64;
  const int wn = (w & 3) * 64;

  f4 acc[4][4];
#pragma unroll
  for (int i = 0; i < 4; ++i)
#pragma unroll
    for (int j = 0; j < 4; ++j) acc[i][j] = (f4){0.f, 0.f, 0.f, 0.f};

  const int rS = t >> 2;
  const int cS = (((t & 3) ^ ((t >> 3) & 3))) * 8;
  const unsigned short* gA = A + (size_t)(m0 + rS) * lda + cS;
  const unsigned short* gB = Bm + (size_t)(n0 + rS) * ldb + cS;
  const long rowStepB = (long)128 * ldb;
  const int r16 = lane & 15;
  const int sx = (r16 >> 1) & 3;
  const int kg = (((lane >> 4) ^ sx)) * 8;

#define STAGE2(slot, kt)                                                \
  do {                                                                  \
    const unsigned short* sA_ = gA + (size_t)(kt) * BK;                 \
    const unsigned short* sB_ = gB + (size_t)(kt) * BK;                 \
    unsigned short* dA_ = As + (slot) * (BM2 * BK) + t * 8;             \
    unsigned short* dB_ = Bs + (slot) * (BN2 * BK) + t * 8;             \
    GLL(sA_, dA_);                                                      \
    GLL(sB_, dB_);                                                      \
    GLL(sB_ + rowStepB, dB_ + BM2 * BK);                                \
  } while (0)

  const int nIter = Kd / BK;
  STAGE2(0, 0);
  int cur = 0;
  for (int kt = 0; kt < nIter; ++kt) {
    asm volatile("s_waitcnt vmcnt(0)" ::: "memory");
    __builtin_amdgcn_s_barrier();
    asm volatile("" ::: "memory");
    if (kt + 1 < nIter) STAGE2(cur ^ 1, kt + 1);
    const unsigned short* Ab = As + cur * (BM2 * BK);
    const unsigned short* Bb2 = Bs + cur * (BN2 * BK);
    bfrag af[4], bfr[4];
#pragma unroll
    for (int i = 0; i < 4; ++i) {
      af[i]  = *(const bfrag*)(Ab + (wm + i * 16 + r16) * BK + kg);
      bfr[i] = *(const bfrag*)(Bb2 + (wn + i * 16 + r16) * BK + kg);
    }
    __builtin_amdgcn_s_setprio(1);
#pragma unroll
    for (int i = 0; i < 4; ++i)
#pragma unroll
      for (int j = 0; j < 4; ++j)
        acc[i][j] = __builtin_amdgcn_mfma_f32_16x16x32_bf16(af[i], bfr[j], acc[i][j], 0, 0, 0);
    __builtin_amdgcn_s_setprio(0);
    asm volatile("" ::: "memory");
    cur ^= 1;
  }
#undef STAGE2

  const int rowBase = m0 + wm + ((lane >> 4) << 2);
  const int colBase = n0 + wn + (lane & 15);

  if (EPI >= 2) {
    const int kq = lane & 3;
    const int NO = N >> 2;
    float av[4][4];
#pragma unroll
    for (int i = 0; i < 4; ++i)
#pragma unroll
      for (int r = 0; r < 4; ++r)
        av[i][r] = alphaP[(size_t)(rowBase + i * 16 + r) * 4 + kq];
    float* Cf = (float*)Cv + (size_t)zb * sC;
    unsigned short* Cb = (unsigned short*)Cv + (size_t)zb * sC;
#pragma unroll
    for (int i = 0; i < 4; ++i)
#pragma unroll
      for (int j = 0; j < 4; ++j) {
        const int col = colBase + j * 16;
#pragma unroll
        for (int r = 0; r < 4; ++r) {
          float p = av[i][r] * acc[i][j][r];
          p += __shfl_xor(p, 1);
          p += __shfl_xor(p, 2);
          if (kq == 0) {
            const int row = rowBase + i * 16 + r;
            if (EPI == 2) Cf[(size_t)row * NO + (col >> 2)] = p;
            else          Cb[(size_t)row * NO + (col >> 2)] = f2bf(p);
          }
        }
      }
    return;
  }

  float* Cf = (float*)Cv + (size_t)zb * sC;
  unsigned short* Cb = (unsigned short*)Cv + (size_t)zb * sC;
#pragma unroll
  for (int i = 0; i < 4; ++i) {
#pragma unroll
    for (int j = 0; j < 4; ++j) {
      const int col = colBase + j * 16;
#pragma unroll
      for (int r = 0; r < 4; ++r) {
        const int row = rowBase + i * 16 + r;
        float v = acc[i][j][r];
        if (BIAS == 1) v += bias[col];
        if (BIAS == 2) v += bias[row];
        if (EPI == 1) Cb[(size_t)row * N + col] = f2bf(v);
        else          Cf[(size_t)row * N + col] = v;
      }
    }
  }
}

// ---- engine w8: 512-thread 8-wave 128x128 (per-wave 64x32), 3-slot counted vmcnt.
template <int BIAS, int EPI /*0 f32,1 bf16*/>
__global__ __launch_bounds__(512, 2) void gemm_w8(
    const unsigned short* __restrict__ A, long sA,
    const unsigned short* __restrict__ Bm, long sB,
    const float* __restrict__ bias, long bS,
    void* __restrict__ Cv, long sC,
    int M, int N, int Kd, int lda, int ldb) {
  const int zb = blockIdx.z;
  A += (size_t)zb * sA;
  Bm += (size_t)zb * sB;
  if (BIAS) bias += (size_t)zb * bS;
  const int m0 = blockIdx.x * BM;
  const int n0 = blockIdx.y * BN;
  __shared__ __attribute__((aligned(16))) unsigned short As[3 * BM * BK]; // 24 KB
  __shared__ __attribute__((aligned(16))) unsigned short Bs[3 * BN * BK]; // 24 KB
  const int t = threadIdx.x;
  const int lane = t & 63;
  const int w = t >> 6;
  const int wm = (w >> 2) * 64;
  const int wn = (w & 3) * 32;

  f4 acc[4][2];
#pragma unroll
  for (int i = 0; i < 4; ++i)
#pragma unroll
    for (int j = 0; j < 2; ++j) acc[i][j] = (f4){0.f, 0.f, 0.f, 0.f};

  const int rS = t >> 2;
  const int cS = (((t & 3) ^ ((t >> 3) & 3))) * 8;
  const unsigned short* gA = A + (size_t)(m0 + rS) * lda + cS;
  const unsigned short* gB = Bm + (size_t)(n0 + rS) * ldb + cS;
  const int r16 = lane & 15;
  const int sx = (r16 >> 1) & 3;
  const int kg = (((lane >> 4) ^ sx)) * 8;

#define STAGEW(slot, kt)                                                \
  do {                                                                  \
    GLL(gA + (size_t)(kt) * BK, As + (slot) * (BM * BK) + t * 8);       \
    GLL(gB + (size_t)(kt) * BK, Bs + (slot) * (BN * BK) + t * 8);       \
  } while (0)

  const int nIter = Kd / BK;
  STAGEW(0, 0);
  STAGEW(1, 1);
  int slot = 0;
  for (int kt = 0; kt < nIter; ++kt) {
    if (kt + 1 < nIter) asm volatile("s_waitcnt vmcnt(2)" ::: "memory");
    else                asm volatile("s_waitcnt vmcnt(0)" ::: "memory");
    __builtin_amdgcn_s_barrier();
    asm volatile("" ::: "memory");
    if (kt + 2 < nIter) {
      int s2 = slot + 2; if (s2 >= 3) s2 -= 3;
      STAGEW(s2, kt + 2);
    }
    const unsigned short* Ab = As + slot * (BM * BK);
    const unsigned short* Bb2 = Bs + slot * (BN * BK);
    bfrag af[4], bfr[2];
#pragma unroll
    for (int i = 0; i < 4; ++i)
      af[i]  = *(const bfrag*)(Ab + (wm + i * 16 + r16) * BK + kg);
#pragma unroll
    for (int j = 0; j < 2; ++j)
      bfr[j] = *(const bfrag*)(Bb2 + (wn + j * 16 + r16) * BK + kg);
    __builtin_amdgcn_s_setprio(1);
#pragma unroll
    for (int i = 0; i < 4; ++i)
#pragma unroll
      for (int j = 0; j < 2; ++j)
        acc[i][j] = __builtin_amdgcn_mfma_f32_16x16x32_bf16(af[i], bfr[j], acc[i][j], 0, 0, 0);
    __builtin_amdgcn_s_setprio(0);
    asm volatile("" ::: "memory");
    slot = (slot == 2) ? 0 : slot + 1;
  }
#undef STAGEW

  const int rowBase = m0 + wm + ((lane >> 4) << 2);
  const int colBase = n0 + wn + (lane & 15);
  float* Cf = (float*)Cv + (size_t)zb * sC;
  unsigned short* Cb = (unsigned short*)Cv + (size_t)zb * sC;
#pragma unroll
  for (int i = 0; i < 4; ++i) {
#pragma unroll
    for (int j = 0; j < 2; ++j) {
      const int col = colBase + j * 16;
#pragma unroll
      for (int r = 0; r < 4; ++r) {
        const int row = rowBase + i * 16 + r;
        float v = acc[i][j][r];
        if (BIAS == 1) v += bias[col];
        if (BIAS == 2) v += bias[row];
        if (EPI == 1) Cb[(size_t)row * N + col] = f2bf(v);
        else          Cf[(size_t)row * N + col] = v;
      }
    }
  }
}

// ---- fused gating: hmid GEMM (M=BL, N=DH=128, K=256 full) + GELU + Wa2 + softmax.
__global__ __launch_bounds__(512, 2) void gemm_alpha(
    const unsigned short* __restrict__ A,    // thf (BL x D_)
    const unsigned short* __restrict__ Bm,   // Wa1b (DH x D_)
    const float* __restrict__ ba1, const float* __restrict__ Wa2,
    const float* __restrict__ ba2, float* __restrict__ alphaOut) {
  __shared__ __attribute__((aligned(16))) unsigned short smem[6 * BM * BK + 1344];
  unsigned short* As = smem;                  // 3 slots x 128x32
  unsigned short* Bs = smem + 3 * BM * BK;    // 3 slots x 128x32
  unsigned short* tile = smem;                // epilogue alias: 128x128 bf16 = 32 KB
  float* w2s = (float*)(smem + 6 * BM * BK);  // 512 f32
  float* b1s = w2s + 512;                     // 128 f32
  float* b2s = b1s + 128;                     // 4 f32
  const int t = threadIdx.x;
  const int lane = t & 63;
  const int w = t >> 6;
  const int wm = (w >> 2) * 64;
  const int wn = (w & 3) * 32;
  const int m0 = blockIdx.x * BM;

  f4 acc[4][2];
#pragma unroll
  for (int i = 0; i < 4; ++i)
#pragma unroll
    for (int j = 0; j < 2; ++j) acc[i][j] = (f4){0.f, 0.f, 0.f, 0.f};

  const int rS = t >> 2;
  const int cS = (((t & 3) ^ ((t >> 3) & 3))) * 8;
  const unsigned short* gA = A + (size_t)(m0 + rS) * D_ + cS;
  const unsigned short* gB = Bm + (size_t)rS * D_ + cS;
  const int r16 = lane & 15;
  const int sx = (r16 >> 1) & 3;
  const int kg = (((lane >> 4) ^ sx)) * 8;

#define STAGEA(slot, kt)                                                \
  do {                                                                  \
    GLL(gA + (size_t)(kt) * BK, As + (slot) * (BM * BK) + t * 8);       \
    GLL(gB + (size_t)(kt) * BK, Bs + (slot) * (BM * BK) + t * 8);       \
  } while (0)

  const int nIter = D_ / BK;   // 8
  STAGEA(0, 0);
  STAGEA(1, 1);
  int slot = 0;
  for (int kt = 0; kt < nIter; ++kt) {
    if (kt + 1 < nIter) asm volatile("s_waitcnt vmcnt(2)" ::: "memory");
    else                asm volatile("s_waitcnt vmcnt(0)" ::: "memory");
    __builtin_amdgcn_s_barrier();
    asm volatile("" ::: "memory");
    if (kt + 2 < nIter) {
      int s2 = slot + 2; if (s2 >= 3) s2 -= 3;
      STAGEA(s2, kt + 2);
    }
    const unsigned short* Ab = As + slot * (BM * BK);
    const unsigned short* Bb2 = Bs + slot * (BM * BK);
    bfrag af[4], bfr[2];
#pragma unroll
    for (int i = 0; i < 4; ++i)
      af[i]  = *(const bfrag*)(Ab + (wm + i * 16 + r16) * BK + kg);
#pragma unroll
    for (int j = 0; j < 2; ++j)
      bfr[j] = *(const bfrag*)(Bb2 + (wn + j * 16 + r16) * BK + kg);
    __builtin_amdgcn_s_setprio(1);
#pragma unroll
    for (int i = 0; i < 4; ++i)
#pragma unroll
      for (int j = 0; j < 2; ++j)
        acc[i][j] = __builtin_amdgcn_mfma_f32_16x16x32_bf16(af[i], bfr[j], acc[i][j], 0, 0, 0);
    __builtin_amdgcn_s_setprio(0);
    asm volatile("" ::: "memory");
    slot = (slot == 2) ? 0 : slot + 1;
  }
#undef STAGEA

  __syncthreads();
  w2s[t & 511] = Wa2[t & 511];
  if (t < DH) b1s[t] = ba1[t];
  if (t < K_) b2s[t] = ba2[t];
  const int lrowBase = wm + ((lane >> 4) << 2);
  const int lcolBase = wn + r16;
#pragma unroll
  for (int i = 0; i < 4; ++i)
#pragma unroll
    for (int j = 0; j < 2; ++j) {
      const int col = lcolBase + j * 16;
#pragma unroll
      for (int r = 0; r < 4; ++r)
        tile[(lrowBase + i * 16 + r) * DH + col] = f2bf(acc[i][j][r]);
    }
  __syncthreads();

  const int tok = t >> 2;
  const int q = t & 3;
  float a0 = 0.f, a1 = 0.f, a2 = 0.f, a3 = 0.f;
#pragma unroll 8
  for (int e = 0; e < 32; ++e) {
    const int d = q * 32 + e;
    float g = bf2f(tile[tok * DH + d]) + b1s[d];
    g = 0.5f * g * (1.0f + erff(g * 0.70710678118654752f));
    a0 += g * w2s[0 * DH + d];
    a1 += g * w2s[1 * DH + d];
    a2 += g * w2s[2 * DH + d];
    a3 += g * w2s[3 * DH + d];
  }
  a0 += __shfl_xor(a0, 1); a1 += __shfl_xor(a1, 1); a2 += __shfl_xor(a2, 1); a3 += __shfl_xor(a3, 1);
  a0 += __shfl_xor(a0, 2); a1 += __shfl_xor(a1, 2); a2 += __shfl_xor(a2, 2); a3 += __shfl_xor(a3, 2);
  a0 += b2s[0]; a1 += b2s[1]; a2 += b2s[2]; a3 += b2s[3];
  float m = fmaxf(fmaxf(a0, a1), fmaxf(a2, a3));
  float e0 = expf(a0 - m), e1 = expf(a1 - m), e2 = expf(a2 - m), e3 = expf(a3 - m);
  float inv = 1.f / (e0 + e1 + e2 + e3);
  float my = (q == 0) ? e0 : (q == 1) ? e1 : (q == 2) ? e2 : e3;
  alphaOut[(size_t)(m0 + tok) * 4 + q] = my * inv;
}

// ---------------------------------------------------------------- launch

extern "C" void kernel_launch(void* const* d_in, const int* in_sizes, int n_in,
                              void* d_out, int out_size, void* d_ws, size_t ws_size,
                              hipStream_t stream) {
  const float* feat  = (const float*)d_in[0];
  const float* hf    = (const float*)d_in[1];
  const float* Wf    = (const float*)d_in[2];
  const float* bfv   = (const float*)d_in[3];
  const float* Whf   = (const float*)d_in[4];
  const float* bhfv  = (const float*)d_in[5];
  const float* Wa1   = (const float*)d_in[6];
  const float* ba1   = (const float*)d_in[7];
  const float* Wa2   = (const float*)d_in[8];
  const float* ba2   = (const float*)d_in[9];
  const float* Abase = (const float*)d_in[10];
  const float* Bbase = (const float*)d_in[11];
  const float* Cbase = (const float*)d_in[12];
  const float* Wout  = (const float*)d_in[13];
  const float* bout  = (const float*)d_in[14];
  float* out = (float*)d_out;

  char* ws = (char*)d_ws;
  size_t off = 0;
  auto alloc = [&](size_t bytes) { void* p = ws + off; off += bytes; return p; };

  unsigned short* Wfb    = (unsigned short*)alloc((size_t)2 * D_ * CIN * 2); // Wfb+Whfb
  unsigned short* Wa1b   = (unsigned short*)alloc((size_t)DH * D_ * 2);
  unsigned short* Woutb  = (unsigned short*)alloc((size_t)CIN * D_ * 2);
  unsigned short* Bb16   = (unsigned short*)alloc((size_t)K_ * N_ * D_ * 2);
  unsigned short* Cb16   = (unsigned short*)alloc((size_t)K_ * D_ * N_ * 2);
  float*          biascat= (float*)alloc((size_t)2 * D_ * 4);
  float*          alpha  = (float*)alloc((size_t)BL * K_ * 4);
  float*          Pc     = (float*)alloc((size_t)B_ * NCHUNK * N_ * 4);
  float*          He     = (float*)alloc((size_t)B_ * NCHUNK * N_ * 4);
  float*          Hs     = (float*)alloc((size_t)B_ * NCHUNK * N_ * 4);
  unsigned short* hbf    = (unsigned short*)alloc((size_t)BL * N_ * 2);
  unsigned short* x      = (unsigned short*)alloc((size_t)BL * D_ * 2);
  unsigned short* thf    = (unsigned short*)alloc((size_t)BL * D_ * 2);
  unsigned short* featT  = (unsigned short*)alloc((size_t)BL * CIN * 2);
  unsigned short* hfT    = (unsigned short*)alloc((size_t)BL * CIN * 2);
  unsigned short* u16    = (unsigned short*)alloc((size_t)BL * N_ * 2);   // 16.8 MB

  // aliases (dead regions)
  unsigned short* y   = thf;            // BL*D bf16, thf dead after gemm_alpha

  if (ws_size < off) return;  // ~78 MB required

  // 1) weight conversions + base relayouts
  k_prep<<<dim3((3 * 65536 + 32768 + 2 * 524288 + 512 + 255) / 256), 256, 0, stream>>>(
      Wf, Whf, Wa1, Wout, Bbase, Cbase, bfv, bhfv, Wfb, Wa1b, Woutb, Bb16, Cb16, biascat);

  // 2) token-major transposed inputs (batched feat+hf)
  k_transpose2<<<dim3(L_ / 32, CIN / 32, 2 * B_), dim3(32, 8), 0, stream>>>(feat, hf, featT);

  // 3) projections batched z=2: x = featT@Wf^T+bf ; thf = hfT@Whf^T+bhf  (8-wave 128²)
  gemm_w8<1, 1><<<dim3(BL / BM, D_ / BN, 2), 512, 0, stream>>>(
      featT, (long)BL * CIN, Wfb, (long)D_ * CIN, biascat, D_,
      x, (long)BL * D_, BL, D_, CIN, CIN, CIN);

  // 4) fused gating: hmid GEMM (full K) + GELU + Wa2 + softmax -> alpha
  gemm_alpha<<<dim3(BL / BM), 512, 0, stream>>>(thf, Wa1b, ba1, Wa2, ba2, alpha);

  // 5) u[t,n] = sum_k alpha_k (x @ B_base^T) : engine2 (2-slot), EPI=3
  gemm_bt2<0, 3><<<dim3(BL / BM2, (K_ * N_) / BN2, 1), 512, 0, stream>>>(
      x, 0, Bb16, 0, nullptr, 0, alpha, u16, 0, BL, K_ * N_, D_, D_, D_);

  // 6) chunked scan (NCHUNK=256 -> 1024 blocks, CLEN=16); pass C writes h (bf16)
  k_scanA<<<dim3(B_ * NCHUNK), N_, 0, stream>>>(u16, alpha, Abase, Pc, He);
  k_scanB<<<dim3(B_), N_, 0, stream>>>(Pc, He, Hs);
  k_scanC<<<dim3(B_ * NCHUNK), N_, 0, stream>>>(u16, alpha, Abase, Hs, hbf);

  // 7) y[t,d] = sum_k alpha_k (h @ C_base^T) : engine2 (2-slot), EPI=3
  gemm_bt2<0, 3><<<dim3(BL / BM2, (K_ * D_) / BN2, 1), 512, 0, stream>>>(
      hbf, 0, Cb16, 0, nullptr, 0, alpha, y, 0, BL, K_ * D_, N_, N_, N_);

  // 8) out[b,c,l] = Wout @ y_b^T + bout : batched z=4 (8-wave 128²)
  gemm_w8<2, 0><<<dim3(CIN / BM, L_ / BN, B_), 512, 0, stream>>>(
      Woutb, 0, y, (long)L_ * D_, bout, 0, out, (long)CIN * L_, CIN, L_, D_, D_, D_);
}

// Round 18
// 139.731 us; speedup vs baseline: 1.0662x; 1.0662x over previous
//
#include <hip/hip_runtime.h>
#include <hip/hip_bf16.h>
#include <math.h>

// Dims (fixed by the problem)
#define B_  4
#define CIN 256
#define L_  4096      // H*W = 64*64
#define D_  256
#define N_  512
#define K_  4
#define DH  128       // D/2
#define BL  (B_ * L_) // 16384 tokens

#define NCHUNK 128
#define CLEN   (L_ / NCHUNK) // 32

typedef __attribute__((ext_vector_type(8))) short bfrag;
typedef __attribute__((ext_vector_type(4))) float f4;

__device__ __forceinline__ float bf2f(unsigned short u) {
  return __uint_as_float(((unsigned int)u) << 16);
}
__device__ __forceinline__ unsigned short f2bf(float f) {
  unsigned int u = __float_as_uint(f);
  return (unsigned short)((u + 0x7FFFu + ((u >> 16) & 1u)) >> 16);
}

// ---------------------------------------------------------------- prep (all weight converts, 1 launch)
// Bb16 row (n*4+k) = B_base[k,n,:]   (K-contig over d)
// Cb16 row (d*4+k) = C_base[k,d,:]   (K-contig over n)
__global__ void k_prep(const float* __restrict__ Wf, const float* __restrict__ Whf,
                       const float* __restrict__ Wa1, const float* __restrict__ Wout,
                       const float* __restrict__ Bb, const float* __restrict__ Cb,
                       const float* __restrict__ bfv, const float* __restrict__ bhfv,
                       unsigned short* __restrict__ Wfb /*Wfb+Whfb adjacent*/,
                       unsigned short* __restrict__ Wa1b,
                       unsigned short* __restrict__ Woutb,
                       unsigned short* __restrict__ Bb16,
                       unsigned short* __restrict__ Cb16,
                       float* __restrict__ biascat) {
  int i = blockIdx.x * 256 + threadIdx.x;
  if (i < 65536) { Wfb[i] = f2bf(Wf[i]); return; } i -= 65536;
  if (i < 65536) { Wfb[65536 + i] = f2bf(Whf[i]); return; } i -= 65536;
  if (i < 32768) { Wa1b[i] = f2bf(Wa1[i]); return; } i -= 32768;
  if (i < 65536) { Woutb[i] = f2bf(Wout[i]); return; } i -= 65536;
  if (i < 524288) {  // B_base (K,N,D): i = (k<<17)|(n<<8)|d
    int d = i & 255, n = (i >> 8) & 511, k = i >> 17;
    Bb16[(((size_t)n << 2) | k) << 8 | d] = f2bf(Bb[i]);
    return;
  } i -= 524288;
  if (i < 524288) {  // C_base (K,D,N): i = (k<<17)|(d<<9)|nn
    int nn = i & 511, d = (i >> 9) & 255, k = i >> 17;
    Cb16[(((size_t)d << 2) | k) << 9 | nn] = f2bf(Cb[i]);
    return;
  } i -= 524288;
  if (i < 256) { biascat[i] = bfv[i]; return; } i -= 256;
  if (i < 256) { biascat[256 + i] = bhfv[i]; }
}

// feat/hf (B,C,L) f32 -> (B*L, C) bf16 ; z = which*4 + b
__global__ void k_transpose2(const float* __restrict__ feat, const float* __restrict__ hf,
                             unsigned short* __restrict__ featT /* hfT adjacent */) {
  __shared__ float tile[32][33];
  const int z = blockIdx.z;
  const int b = z & 3, which = z >> 2;
  const float* in = which ? hf : feat;
  unsigned short* outT = featT + (size_t)which * BL * CIN;
  const int l0 = blockIdx.x * 32, c0 = blockIdx.y * 32;
  const int tx = threadIdx.x, ty = threadIdx.y;
  const float* p = in + ((size_t)b * CIN + c0 + ty) * L_ + l0 + tx;
#pragma unroll
  for (int i = 0; i < 32; i += 8) tile[ty + i][tx] = p[(size_t)i * L_];
  __syncthreads();
  unsigned short* q = outT + ((size_t)b * L_ + l0 + ty) * CIN + c0 + tx;
#pragma unroll
  for (int i = 0; i < 32; i += 8) q[(size_t)i * CIN] = f2bf(tile[tx][ty + i]);
}

// ---------------------------------------------------------------- scan (3-pass)
// a recomputed from alpha & A_base in-register; u read as bf16.

__global__ void k_scanA(const unsigned short* __restrict__ u, const float* __restrict__ alpha,
                        const float* __restrict__ Abase,
                        float* __restrict__ P, float* __restrict__ Hend) {
  const int n = threadIdx.x;           // 512
  const int bc = blockIdx.x;           // B*NCHUNK = 512
  const int b = bc >> 7, c = bc & 127;
  const float A0 = Abase[n], A1 = Abase[N_ + n], A2 = Abase[2 * N_ + n], A3 = Abase[3 * N_ + n];
  const size_t tok0 = (size_t)b * L_ + (size_t)c * CLEN;
  float p = 1.f, h = 0.f;
  for (int l = 0; l < CLEN; ++l) {
    const size_t t = tok0 + l;
    float4 al = *(const float4*)(alpha + t * 4);
    float s = al.x * A0 + al.y * A1 + al.z * A2 + al.w * A3;
    float av = 1.f / (1.f + expf(-s));
    float uv = bf2f(u[t * N_ + n]);
    h = av * h + uv;
    p *= av;
  }
  P[(size_t)bc * N_ + n] = p;
  Hend[(size_t)bc * N_ + n] = h;
}

__global__ void k_scanB(const float* __restrict__ P, const float* __restrict__ Hend,
                        float* __restrict__ Hstart) {
  const int n = threadIdx.x;
  const int b = blockIdx.x;
  float h = 0.f;
  for (int c = 0; c < NCHUNK; ++c) {
    size_t idx = ((size_t)b * NCHUNK + c) * N_ + n;
    Hstart[idx] = h;
    h = P[idx] * h + Hend[idx];
  }
}

__global__ void k_scanC(const unsigned short* __restrict__ u, const float* __restrict__ alpha,
                        const float* __restrict__ Abase, const float* __restrict__ Hstart,
                        unsigned short* __restrict__ hbf) {
  const int n = threadIdx.x;
  const int bc = blockIdx.x;
  const int b = bc >> 7, c = bc & 127;
  const float A0 = Abase[n], A1 = Abase[N_ + n], A2 = Abase[2 * N_ + n], A3 = Abase[3 * N_ + n];
  const size_t tok0 = (size_t)b * L_ + (size_t)c * CLEN;
  float h = Hstart[(size_t)bc * N_ + n];
  for (int l = 0; l < CLEN; ++l) {
    const size_t t = tok0 + l;
    float4 al = *(const float4*)(alpha + t * 4);
    float s = al.x * A0 + al.y * A1 + al.z * A2 + al.w * A3;
    float av = 1.f / (1.f + expf(-s));
    float uv = bf2f(u[t * N_ + n]);
    h = av * h + uv;
    hbf[t * N_ + n] = f2bf(h);
  }
}

// ---------------------------------------------------------------- GEMM common
// LDS XOR swizzle (T2, rule #21 both-sides): 64-B rows, slot(16B) ^= (row>>1)&3.
#define BM 128
#define BN 128
#define BK 32

#define GLL(src, dst)                                                                      \
  __builtin_amdgcn_global_load_lds((const __attribute__((address_space(1))) void*)(src),   \
                                   (__attribute__((address_space(3))) void*)(dst), 16, 0, 0)

// ---- engine 2: 512-thread 128x256, 2-SLOT LDS (48 KB -> 3 blocks/CU), counted
// vmcnt + raw barrier. EPI: 3 = alpha-mix -> bf16 (ld=N/4).
#define BM2 128
#define BN2 256

template <int BIAS, int EPI>
__global__ __launch_bounds__(512, 2) void gemm_bt2(
    const unsigned short* __restrict__ A, long sA,
    const unsigned short* __restrict__ Bm, long sB,
    const float* __restrict__ bias, long bS,
    const float* __restrict__ alphaP,
    void* __restrict__ Cv, long sC,
    int M, int N, int Kd, int lda, int ldb) {
  const int zb = blockIdx.z;
  A += (size_t)zb * sA;
  Bm += (size_t)zb * sB;
  if (BIAS) bias += (size_t)zb * bS;
  const int m0 = blockIdx.x * BM2;
  const int n0 = blockIdx.y * BN2;
  __shared__ __attribute__((aligned(16))) unsigned short As[2 * BM2 * BK]; // 16 KB
  __shared__ __attribute__((aligned(16))) unsigned short Bs[2 * BN2 * BK]; // 32 KB
  const int t = threadIdx.x;
  const int lane = t & 63;
  const int w = t >> 6;
  const int wm = (w >> 2) * 64;
  const int wn = (w & 3) * 64;

  f4 acc[4][4];
#pragma unroll
  for (int i = 0; i < 4; ++i)
#pragma unroll
    for (int j = 0; j < 4; ++j) acc[i][j] = (f4){0.f, 0.f, 0.f, 0.f};

  const int rS = t >> 2;
  const int cS = (((t & 3) ^ ((t >> 3) & 3))) * 8;
  const unsigned short* gA = A + (size_t)(m0 + rS) * lda + cS;
  const unsigned short* gB = Bm + (size_t)(n0 + rS) * ldb + cS;
  const long rowStepB = (long)128 * ldb;
  const int r16 = lane & 15;
  const int sx = (r16 >> 1) & 3;
  const int kg = (((lane >> 4) ^ sx)) * 8;

#define STAGE2(slot, kt)                                                \
  do {                                                                  \
    const unsigned short* sA_ = gA + (size_t)(kt) * BK;                 \
    const unsigned short* sB_ = gB + (size_t)(kt) * BK;                 \
    unsigned short* dA_ = As + (slot) * (BM2 * BK) + t * 8;             \
    unsigned short* dB_ = Bs + (slot) * (BN2 * BK) + t * 8;             \
    GLL(sA_, dA_);                                                      \
    GLL(sB_, dB_);                                                      \
    GLL(sB_ + rowStepB, dB_ + BM2 * BK);                                \
  } while (0)

  const int nIter = Kd / BK;
  STAGE2(0, 0);
  int cur = 0;
  for (int kt = 0; kt < nIter; ++kt) {
    asm volatile("s_waitcnt vmcnt(0)" ::: "memory");
    __builtin_amdgcn_s_barrier();
    asm volatile("" ::: "memory");
    if (kt + 1 < nIter) STAGE2(cur ^ 1, kt + 1);
    const unsigned short* Ab = As + cur * (BM2 * BK);
    const unsigned short* Bb2 = Bs + cur * (BN2 * BK);
    bfrag af[4], bfr[4];
#pragma unroll
    for (int i = 0; i < 4; ++i) {
      af[i]  = *(const bfrag*)(Ab + (wm + i * 16 + r16) * BK + kg);
      bfr[i] = *(const bfrag*)(Bb2 + (wn + i * 16 + r16) * BK + kg);
    }
    __builtin_amdgcn_s_setprio(1);
#pragma unroll
    for (int i = 0; i < 4; ++i)
#pragma unroll
      for (int j = 0; j < 4; ++j)
        acc[i][j] = __builtin_amdgcn_mfma_f32_16x16x32_bf16(af[i], bfr[j], acc[i][j], 0, 0, 0);
    __builtin_amdgcn_s_setprio(0);
    asm volatile("" ::: "memory");
    cur ^= 1;
  }
#undef STAGE2

  const int rowBase = m0 + wm + ((lane >> 4) << 2);
  const int colBase = n0 + wn + (lane & 15);

  if (EPI >= 2) {
    const int kq = lane & 3;
    const int NO = N >> 2;
    float av[4][4];
#pragma unroll
    for (int i = 0; i < 4; ++i)
#pragma unroll
      for (int r = 0; r < 4; ++r)
        av[i][r] = alphaP[(size_t)(rowBase + i * 16 + r) * 4 + kq];
    float* Cf = (float*)Cv + (size_t)zb * sC;
    unsigned short* Cb = (unsigned short*)Cv + (size_t)zb * sC;
#pragma unroll
    for (int i = 0; i < 4; ++i)
#pragma unroll
      for (int j = 0; j < 4; ++j) {
        const int col = colBase + j * 16;
#pragma unroll
        for (int r = 0; r < 4; ++r) {
          float p = av[i][r] * acc[i][j][r];
          p += __shfl_xor(p, 1);
          p += __shfl_xor(p, 2);
          if (kq == 0) {
            const int row = rowBase + i * 16 + r;
            if (EPI == 2) Cf[(size_t)row * NO + (col >> 2)] = p;
            else          Cb[(size_t)row * NO + (col >> 2)] = f2bf(p);
          }
        }
      }
    return;
  }

  float* Cf = (float*)Cv + (size_t)zb * sC;
  unsigned short* Cb = (unsigned short*)Cv + (size_t)zb * sC;
#pragma unroll
  for (int i = 0; i < 4; ++i) {
#pragma unroll
    for (int j = 0; j < 4; ++j) {
      const int col = colBase + j * 16;
#pragma unroll
      for (int r = 0; r < 4; ++r) {
        const int row = rowBase + i * 16 + r;
        float v = acc[i][j][r];
        if (BIAS == 1) v += bias[col];
        if (BIAS == 2) v += bias[row];
        if (EPI == 1) Cb[(size_t)row * N + col] = f2bf(v);
        else          Cf[(size_t)row * N + col] = v;
      }
    }
  }
}

// ---- engine w8: 512-thread 8-wave 128x128 (per-wave 64x32), 3-slot counted vmcnt.
template <int BIAS, int EPI /*0 f32,1 bf16*/>
__global__ __launch_bounds__(512, 2) void gemm_w8(
    const unsigned short* __restrict__ A, long sA,
    const unsigned short* __restrict__ Bm, long sB,
    const float* __restrict__ bias, long bS,
    void* __restrict__ Cv, long sC,
    int M, int N, int Kd, int lda, int ldb) {
  const int zb = blockIdx.z;
  A += (size_t)zb * sA;
  Bm += (size_t)zb * sB;
  if (BIAS) bias += (size_t)zb * bS;
  const int m0 = blockIdx.x * BM;
  const int n0 = blockIdx.y * BN;
  __shared__ __attribute__((aligned(16))) unsigned short As[3 * BM * BK]; // 24 KB
  __shared__ __attribute__((aligned(16))) unsigned short Bs[3 * BN * BK]; // 24 KB
  const int t = threadIdx.x;
  const int lane = t & 63;
  const int w = t >> 6;
  const int wm = (w >> 2) * 64;
  const int wn = (w & 3) * 32;

  f4 acc[4][2];
#pragma unroll
  for (int i = 0; i < 4; ++i)
#pragma unroll
    for (int j = 0; j < 2; ++j) acc[i][j] = (f4){0.f, 0.f, 0.f, 0.f};

  const int rS = t >> 2;
  const int cS = (((t & 3) ^ ((t >> 3) & 3))) * 8;
  const unsigned short* gA = A + (size_t)(m0 + rS) * lda + cS;
  const unsigned short* gB = Bm + (size_t)(n0 + rS) * ldb + cS;
  const int r16 = lane & 15;
  const int sx = (r16 >> 1) & 3;
  const int kg = (((lane >> 4) ^ sx)) * 8;

#define STAGEW(slot, kt)                                                \
  do {                                                                  \
    GLL(gA + (size_t)(kt) * BK, As + (slot) * (BM * BK) + t * 8);       \
    GLL(gB + (size_t)(kt) * BK, Bs + (slot) * (BN * BK) + t * 8);       \
  } while (0)

  const int nIter = Kd / BK;
  STAGEW(0, 0);
  STAGEW(1, 1);
  int slot = 0;
  for (int kt = 0; kt < nIter; ++kt) {
    if (kt + 1 < nIter) asm volatile("s_waitcnt vmcnt(2)" ::: "memory");
    else                asm volatile("s_waitcnt vmcnt(0)" ::: "memory");
    __builtin_amdgcn_s_barrier();
    asm volatile("" ::: "memory");
    if (kt + 2 < nIter) {
      int s2 = slot + 2; if (s2 >= 3) s2 -= 3;
      STAGEW(s2, kt + 2);
    }
    const unsigned short* Ab = As + slot * (BM * BK);
    const unsigned short* Bb2 = Bs + slot * (BN * BK);
    bfrag af[4], bfr[2];
#pragma unroll
    for (int i = 0; i < 4; ++i)
      af[i]  = *(const bfrag*)(Ab + (wm + i * 16 + r16) * BK + kg);
#pragma unroll
    for (int j = 0; j < 2; ++j)
      bfr[j] = *(const bfrag*)(Bb2 + (wn + j * 16 + r16) * BK + kg);
    __builtin_amdgcn_s_setprio(1);
#pragma unroll
    for (int i = 0; i < 4; ++i)
#pragma unroll
      for (int j = 0; j < 2; ++j)
        acc[i][j] = __builtin_amdgcn_mfma_f32_16x16x32_bf16(af[i], bfr[j], acc[i][j], 0, 0, 0);
    __builtin_amdgcn_s_setprio(0);
    asm volatile("" ::: "memory");
    slot = (slot == 2) ? 0 : slot + 1;
  }
#undef STAGEW

  const int rowBase = m0 + wm + ((lane >> 4) << 2);
  const int colBase = n0 + wn + (lane & 15);
  float* Cf = (float*)Cv + (size_t)zb * sC;
  unsigned short* Cb = (unsigned short*)Cv + (size_t)zb * sC;
#pragma unroll
  for (int i = 0; i < 4; ++i) {
#pragma unroll
    for (int j = 0; j < 2; ++j) {
      const int col = colBase + j * 16;
#pragma unroll
      for (int r = 0; r < 4; ++r) {
        const int row = rowBase + i * 16 + r;
        float v = acc[i][j][r];
        if (BIAS == 1) v += bias[col];
        if (BIAS == 2) v += bias[row];
        if (EPI == 1) Cb[(size_t)row * N + col] = f2bf(v);
        else          Cf[(size_t)row * N + col] = v;
      }
    }
  }
}

// ---- fused gating: hmid GEMM (M=BL, N=DH=128, K=256 full) + GELU + Wa2 + softmax.
__global__ __launch_bounds__(512, 2) void gemm_alpha(
    const unsigned short* __restrict__ A,    // thf (BL x D_)
    const unsigned short* __restrict__ Bm,   // Wa1b (DH x D_)
    const float* __restrict__ ba1, const float* __restrict__ Wa2,
    const float* __restrict__ ba2, float* __restrict__ alphaOut) {
  __shared__ __attribute__((aligned(16))) unsigned short smem[6 * BM * BK + 1344];
  unsigned short* As = smem;                  // 3 slots x 128x32
  unsigned short* Bs = smem + 3 * BM * BK;    // 3 slots x 128x32
  unsigned short* tile = smem;                // epilogue alias: 128x128 bf16 = 32 KB
  float* w2s = (float*)(smem + 6 * BM * BK);  // 512 f32
  float* b1s = w2s + 512;                     // 128 f32
  float* b2s = b1s + 128;                     // 4 f32
  const int t = threadIdx.x;
  const int lane = t & 63;
  const int w = t >> 6;
  const int wm = (w >> 2) * 64;
  const int wn = (w & 3) * 32;
  const int m0 = blockIdx.x * BM;

  f4 acc[4][2];
#pragma unroll
  for (int i = 0; i < 4; ++i)
#pragma unroll
    for (int j = 0; j < 2; ++j) acc[i][j] = (f4){0.f, 0.f, 0.f, 0.f};

  const int rS = t >> 2;
  const int cS = (((t & 3) ^ ((t >> 3) & 3))) * 8;
  const unsigned short* gA = A + (size_t)(m0 + rS) * D_ + cS;
  const unsigned short* gB = Bm + (size_t)rS * D_ + cS;
  const int r16 = lane & 15;
  const int sx = (r16 >> 1) & 3;
  const int kg = (((lane >> 4) ^ sx)) * 8;

#define STAGEA(slot, kt)                                                \
  do {                                                                  \
    GLL(gA + (size_t)(kt) * BK, As + (slot) * (BM * BK) + t * 8);       \
    GLL(gB + (size_t)(kt) * BK, Bs + (slot) * (BM * BK) + t * 8);       \
  } while (0)

  const int nIter = D_ / BK;   // 8
  STAGEA(0, 0);
  STAGEA(1, 1);
  int slot = 0;
  for (int kt = 0; kt < nIter; ++kt) {
    if (kt + 1 < nIter) asm volatile("s_waitcnt vmcnt(2)" ::: "memory");
    else                asm volatile("s_waitcnt vmcnt(0)" ::: "memory");
    __builtin_amdgcn_s_barrier();
    asm volatile("" ::: "memory");
    if (kt + 2 < nIter) {
      int s2 = slot + 2; if (s2 >= 3) s2 -= 3;
      STAGEA(s2, kt + 2);
    }
    const unsigned short* Ab = As + slot * (BM * BK);
    const unsigned short* Bb2 = Bs + slot * (BM * BK);
    bfrag af[4], bfr[2];
#pragma unroll
    for (int i = 0; i < 4; ++i)
      af[i]  = *(const bfrag*)(Ab + (wm + i * 16 + r16) * BK + kg);
#pragma unroll
    for (int j = 0; j < 2; ++j)
      bfr[j] = *(const bfrag*)(Bb2 + (wn + j * 16 + r16) * BK + kg);
    __builtin_amdgcn_s_setprio(1);
#pragma unroll
    for (int i = 0; i < 4; ++i)
#pragma unroll
      for (int j = 0; j < 2; ++j)
        acc[i][j] = __builtin_amdgcn_mfma_f32_16x16x32_bf16(af[i], bfr[j], acc[i][j], 0, 0, 0);
    __builtin_amdgcn_s_setprio(0);
    asm volatile("" ::: "memory");
    slot = (slot == 2) ? 0 : slot + 1;
  }
#undef STAGEA

  __syncthreads();
  w2s[t & 511] = Wa2[t & 511];
  if (t < DH) b1s[t] = ba1[t];
  if (t < K_) b2s[t] = ba2[t];
  const int lrowBase = wm + ((lane >> 4) << 2);
  const int lcolBase = wn + r16;
#pragma unroll
  for (int i = 0; i < 4; ++i)
#pragma unroll
    for (int j = 0; j < 2; ++j) {
      const int col = lcolBase + j * 16;
#pragma unroll
      for (int r = 0; r < 4; ++r)
        tile[(lrowBase + i * 16 + r) * DH + col] = f2bf(acc[i][j][r]);
    }
  __syncthreads();

  const int tok = t >> 2;
  const int q = t & 3;
  float a0 = 0.f, a1 = 0.f, a2 = 0.f, a3 = 0.f;
#pragma unroll 8
  for (int e = 0; e < 32; ++e) {
    const int d = q * 32 + e;
    float g = bf2f(tile[tok * DH + d]) + b1s[d];
    g = 0.5f * g * (1.0f + erff(g * 0.70710678118654752f));
    a0 += g * w2s[0 * DH + d];
    a1 += g * w2s[1 * DH + d];
    a2 += g * w2s[2 * DH + d];
    a3 += g * w2s[3 * DH + d];
  }
  a0 += __shfl_xor(a0, 1); a1 += __shfl_xor(a1, 1); a2 += __shfl_xor(a2, 1); a3 += __shfl_xor(a3, 1);
  a0 += __shfl_xor(a0, 2); a1 += __shfl_xor(a1, 2); a2 += __shfl_xor(a2, 2); a3 += __shfl_xor(a3, 2);
  a0 += b2s[0]; a1 += b2s[1]; a2 += b2s[2]; a3 += b2s[3];
  float m = fmaxf(fmaxf(a0, a1), fmaxf(a2, a3));
  float e0 = expf(a0 - m), e1 = expf(a1 - m), e2 = expf(a2 - m), e3 = expf(a3 - m);
  float inv = 1.f / (e0 + e1 + e2 + e3);
  float my = (q == 0) ? e0 : (q == 1) ? e1 : (q == 2) ? e2 : e3;
  alphaOut[(size_t)(m0 + tok) * 4 + q] = my * inv;
}

// ---------------------------------------------------------------- launch

extern "C" void kernel_launch(void* const* d_in, const int* in_sizes, int n_in,
                              void* d_out, int out_size, void* d_ws, size_t ws_size,
                              hipStream_t stream) {
  const float* feat  = (const float*)d_in[0];
  const float* hf    = (const float*)d_in[1];
  const float* Wf    = (const float*)d_in[2];
  const float* bfv   = (const float*)d_in[3];
  const float* Whf   = (const float*)d_in[4];
  const float* bhfv  = (const float*)d_in[5];
  const float* Wa1   = (const float*)d_in[6];
  const float* ba1   = (const float*)d_in[7];
  const float* Wa2   = (const float*)d_in[8];
  const float* ba2   = (const float*)d_in[9];
  const float* Abase = (const float*)d_in[10];
  const float* Bbase = (const float*)d_in[11];
  const float* Cbase = (const float*)d_in[12];
  const float* Wout  = (const float*)d_in[13];
  const float* bout  = (const float*)d_in[14];
  float* out = (float*)d_out;

  char* ws = (char*)d_ws;
  size_t off = 0;
  auto alloc = [&](size_t bytes) { void* p = ws + off; off += bytes; return p; };

  unsigned short* Wfb    = (unsigned short*)alloc((size_t)2 * D_ * CIN * 2); // Wfb+Whfb
  unsigned short* Wa1b   = (unsigned short*)alloc((size_t)DH * D_ * 2);
  unsigned short* Woutb  = (unsigned short*)alloc((size_t)CIN * D_ * 2);
  unsigned short* Bb16   = (unsigned short*)alloc((size_t)K_ * N_ * D_ * 2);
  unsigned short* Cb16   = (unsigned short*)alloc((size_t)K_ * D_ * N_ * 2);
  float*          biascat= (float*)alloc((size_t)2 * D_ * 4);
  float*          alpha  = (float*)alloc((size_t)BL * K_ * 4);
  float*          Pc     = (float*)alloc((size_t)B_ * NCHUNK * N_ * 4);
  float*          He     = (float*)alloc((size_t)B_ * NCHUNK * N_ * 4);
  float*          Hs     = (float*)alloc((size_t)B_ * NCHUNK * N_ * 4);
  unsigned short* hbf    = (unsigned short*)alloc((size_t)BL * N_ * 2);
  unsigned short* x      = (unsigned short*)alloc((size_t)BL * D_ * 2);
  unsigned short* thf    = (unsigned short*)alloc((size_t)BL * D_ * 2);
  unsigned short* featT  = (unsigned short*)alloc((size_t)BL * CIN * 2);
  unsigned short* hfT    = (unsigned short*)alloc((size_t)BL * CIN * 2);
  unsigned short* u16    = (unsigned short*)alloc((size_t)BL * N_ * 2);   // 16.8 MB

  // aliases (dead regions)
  unsigned short* y   = thf;            // BL*D bf16, thf dead after gemm_alpha

  if (ws_size < off) return;  // ~74 MB required

  // 1) weight conversions + base relayouts
  k_prep<<<dim3((3 * 65536 + 32768 + 2 * 524288 + 512 + 255) / 256), 256, 0, stream>>>(
      Wf, Whf, Wa1, Wout, Bbase, Cbase, bfv, bhfv, Wfb, Wa1b, Woutb, Bb16, Cb16, biascat);

  // 2) token-major transposed inputs (batched feat+hf)
  k_transpose2<<<dim3(L_ / 32, CIN / 32, 2 * B_), dim3(32, 8), 0, stream>>>(feat, hf, featT);

  // 3) projections batched z=2: x = featT@Wf^T+bf ; thf = hfT@Whf^T+bhf  (8-wave 128²)
  gemm_w8<1, 1><<<dim3(BL / BM, D_ / BN, 2), 512, 0, stream>>>(
      featT, (long)BL * CIN, Wfb, (long)D_ * CIN, biascat, D_,
      x, (long)BL * D_, BL, D_, CIN, CIN, CIN);

  // 4) fused gating: hmid GEMM (full K) + GELU + Wa2 + softmax -> alpha
  gemm_alpha<<<dim3(BL / BM), 512, 0, stream>>>(thf, Wa1b, ba1, Wa2, ba2, alpha);

  // 5) u[t,n] = sum_k alpha_k (x @ B_base^T) : engine2 (2-slot), EPI=3
  gemm_bt2<0, 3><<<dim3(BL / BM2, (K_ * N_) / BN2, 1), 512, 0, stream>>>(
      x, 0, Bb16, 0, nullptr, 0, alpha, u16, 0, BL, K_ * N_, D_, D_, D_);

  // 6) chunked scan; a recomputed in-register; pass C writes h (bf16)
  k_scanA<<<dim3(B_ * NCHUNK), N_, 0, stream>>>(u16, alpha, Abase, Pc, He);
  k_scanB<<<dim3(B_), N_, 0, stream>>>(Pc, He, Hs);
  k_scanC<<<dim3(B_ * NCHUNK), N_, 0, stream>>>(u16, alpha, Abase, Hs, hbf);

  // 7) y[t,d] = sum_k alpha_k (h @ C_base^T) : engine2 (2-slot), EPI=3
  gemm_bt2<0, 3><<<dim3(BL / BM2, (K_ * D_) / BN2, 1), 512, 0, stream>>>(
      hbf, 0, Cb16, 0, nullptr, 0, alpha, y, 0, BL, K_ * D_, N_, N_, N_);

  // 8) out[b,c,l] = Wout @ y_b^T + bout : batched z=4 (8-wave 128²)
  gemm_w8<2, 0><<<dim3(CIN / BM, L_ / BN, B_), 512, 0, stream>>>(
      Woutb, 0, y, (long)L_ * D_, bout, 0, out, (long)CIN * L_, CIN, L_, D_, D_, D_);
}